// Round 2
// baseline (14259.984 us; speedup 1.0000x reference)
//
#include <hip/hip_runtime.h>
#include <hip/hip_bf16.h>

#define T_SEQ 256
#define HID 512
#define G4 2048
#define ASTR 80  // padded LDS row stride (bytes) for 64B rows: bijective, 2-way banks = free

typedef __attribute__((ext_vector_type(8))) short short8;
typedef __attribute__((ext_vector_type(4))) float floatx4;

__device__ inline unsigned short f2bf(float f) {
  union { __hip_bfloat16 h; unsigned short u; } cv;
  cv.h = __float2bfloat16(f);
  return cv.u;
}
__device__ inline float bf2f(unsigned short u) {
  union { unsigned short u; __hip_bfloat16 h; } cv;
  cv.u = u;
  return __bfloat162float(cv.h);
}

// zero the barrier flags (both layers' regions)
__global__ void init_flags(int* flags) { flags[threadIdx.x] = 0; }

// ---------- transpose+convert: src [K][N] f32 -> dst [N][Kpad] bf16 (zero pad) ----------
__global__ __launch_bounds__(256) void transpose_bf16(const float* __restrict__ src,
                                                      unsigned short* __restrict__ dst,
                                                      int K, int N, int Kpad) {
  __shared__ float tile[32][33];
  int n0 = blockIdx.x * 32, k0 = blockIdx.y * 32;
  int tx = threadIdx.x & 31, ty = threadIdx.x >> 5;  // 32 x 8
#pragma unroll
  for (int i = 0; i < 32; i += 8) {
    int k = k0 + ty + i, n = n0 + tx;
    tile[ty + i][tx] = (k < K) ? src[(size_t)k * N + n] : 0.0f;
  }
  __syncthreads();
#pragma unroll
  for (int i = 0; i < 32; i += 8) {
    int n = n0 + ty + i, k = k0 + tx;
    dst[(size_t)n * Kpad + k] = f2bf(tile[tx][ty + i]);
  }
}

// ---------- bf16 MFMA GEMM: C[m][n] = sum_k A[m][k]*B[k][n]; Bt is [n][Kpad] bf16 ----------
// GATHER: A row m = [emb[wid[m]][0..299], predflag[m], 0 pad...]
template <bool GATHER>
__global__ __launch_bounds__(256) void gemm_xg(const void* __restrict__ Asrc,
                                               const int* __restrict__ wid,
                                               const int* __restrict__ pred,
                                               const unsigned short* __restrict__ Bt,
                                               unsigned short* __restrict__ C,
                                               int Kpad) {
  int n0 = blockIdx.x * 64, m0 = blockIdx.y * 64;
  int tid = threadIdx.x, lane = tid & 63, w = tid >> 6;
  int wr = w >> 1, wc = w & 1;
  __shared__ __align__(16) char As[64 * ASTR];
  __shared__ __align__(16) char Bs[64 * ASTR];
  __shared__ int wids[64];
  __shared__ float pf[64];
  if (GATHER) {
    if (tid < 64) {
      wids[tid] = wid[m0 + tid];
      pf[tid] = (float)pred[m0 + tid];
    }
    __syncthreads();
  }
  floatx4 acc[2][2];
#pragma unroll
  for (int a = 0; a < 2; a++)
#pragma unroll
    for (int b = 0; b < 2; b++) acc[a][b] = (floatx4){0.f, 0.f, 0.f, 0.f};

  int row = tid >> 2, part = tid & 3;
  for (int k0 = 0; k0 < Kpad; k0 += 32) {
    short8 av;
    if (GATHER) {
      const float* emb = (const float*)Asrc;
      int kb = k0 + part * 8;
      const float* erow = emb + (size_t)wids[row] * 300;
      float f[8];
      if (kb + 8 <= 300) {
        const float4* p4 = (const float4*)(erow + kb);
        float4 x0 = p4[0], x1 = p4[1];
        f[0] = x0.x; f[1] = x0.y; f[2] = x0.z; f[3] = x0.w;
        f[4] = x1.x; f[5] = x1.y; f[6] = x1.z; f[7] = x1.w;
      } else {
#pragma unroll
        for (int j = 0; j < 8; j++) {
          int k = kb + j;
          f[j] = (k < 300) ? erow[k] : ((k == 300) ? pf[row] : 0.0f);
        }
      }
      short8 v;
#pragma unroll
      for (int j = 0; j < 8; j++) v[j] = (short)f2bf(f[j]);
      av = v;
    } else {
      const unsigned short* A = (const unsigned short*)Asrc;
      av = *(const short8*)(A + (size_t)(m0 + row) * Kpad + k0 + part * 8);
    }
    *(short8*)(As + row * ASTR + part * 16) = av;
    short8 bv = *(const short8*)(Bt + (size_t)(n0 + row) * Kpad + k0 + part * 8);
    *(short8*)(Bs + row * ASTR + part * 16) = bv;
    __syncthreads();
    short8 afr[2], bfr[2];
#pragma unroll
    for (int mr = 0; mr < 2; mr++) {
      int arow = wr * 32 + mr * 16 + (lane & 15);
      afr[mr] = *(const short8*)(As + arow * ASTR + (lane >> 4) * 16);
    }
#pragma unroll
    for (int nc = 0; nc < 2; nc++) {
      int bcol = wc * 32 + nc * 16 + (lane & 15);
      bfr[nc] = *(const short8*)(Bs + bcol * ASTR + (lane >> 4) * 16);
    }
#pragma unroll
    for (int mr = 0; mr < 2; mr++)
#pragma unroll
      for (int nc = 0; nc < 2; nc++)
        acc[mr][nc] = __builtin_amdgcn_mfma_f32_16x16x32_bf16(afr[mr], bfr[nc], acc[mr][nc], 0, 0, 0);
    __syncthreads();
  }
#pragma unroll
  for (int mr = 0; mr < 2; mr++)
#pragma unroll
    for (int nc = 0; nc < 2; nc++)
#pragma unroll
      for (int r = 0; r < 4; r++) {
        int rr = m0 + wr * 32 + mr * 16 + ((lane >> 4) << 2) + r;
        int cc = n0 + wc * 32 + nc * 16 + (lane & 15);
        C[(size_t)rr * G4 + cc] = f2bf(acc[mr][nc][r]);
      }
}

// ---------- persistent masked-LSTM layer ----------
// grid = 256 blocks: bgrp = blk&7 (8 groups of 16 batch rows), jblk = blk>>3 (32 slices of 16 j)
// Each block: U cols (4 gates x 16 j) x 512 k held in registers; c-state in LDS;
// per-step group barrier via device-scope flags (flags zeroed before launch).
// NOTE: Ah swizzle here IS bijective (seg has 6 bits, XOR uses 3) - keep it.
__global__ __launch_bounds__(256, 1) void lstm_layer(const unsigned short* __restrict__ xg,
                                                     const unsigned short* __restrict__ Ut,
                                                     const float* __restrict__ bias,
                                                     const int* __restrict__ wid,
                                                     unsigned short* __restrict__ hseq,
                                                     int* __restrict__ flags) {
  int blk = blockIdx.x;
  int bgrp = blk & 7;
  int jblk = blk >> 3;
  int b0 = bgrp * 16;
  int j0 = jblk * 16;
  int tid = threadIdx.x, lane = tid & 63, w = tid >> 6;

  __shared__ __align__(16) char Ah[16 * 1024];  // h_prev bf16 [16 rows][512 k], XOR-swizzled
  __shared__ float gates[4][16][16];
  __shared__ float cst[16][16];
  __shared__ __align__(16) unsigned short xgt[4][16][16];

  // preload U fragments: wave w handles gate w, cols j0..j0+15
  short8 uf[16];
  int ucol = w * 512 + j0 + (lane & 15);
  {
    const unsigned short* up = Ut + (size_t)ucol * 512 + ((lane >> 4) * 8);
#pragma unroll
    for (int kk = 0; kk < 16; kk++) uf[kk] = *(const short8*)(up + kk * 32);
  }
  float biasv = bias[ucol];

  if (tid < 256) cst[tid >> 4][tid & 15] = 0.0f;
  {
    short8 z = {0, 0, 0, 0, 0, 0, 0, 0};
    for (int i = tid; i < 1024; i += 256) *(short8*)(Ah + i * 16) = z;
  }
  __syncthreads();

  for (int t = 0; t < T_SEQ; t++) {
    if (t > 0) {
      int row = tid >> 4;
#pragma unroll
      for (int q = 0; q < 4; q++) {
        int seg = (tid & 15) + q * 16;
        short8 v = *(const short8*)(hseq + ((size_t)(b0 + row) * T_SEQ + (t - 1)) * HID + seg * 8);
        *(short8*)(Ah + row * 1024 + ((seg * 16) ^ ((row & 7) << 4))) = v;
      }
    }
    {
      int g = tid >> 6, rw = (tid >> 2) & 15, part = tid & 3;
      const unsigned short* src = xg + ((size_t)(b0 + rw) * T_SEQ + t) * G4 + g * 512 + j0 + part * 4;
      *(uint2*)(&xgt[g][rw][part * 4]) = *(const uint2*)src;
    }
    __syncthreads();

    floatx4 acc = (floatx4){0.f, 0.f, 0.f, 0.f};
    {
      int arow = lane & 15;
      int kbase = (lane >> 4) * 16;
      int sw = (arow & 7) << 4;
#pragma unroll
      for (int kk = 0; kk < 16; kk++) {
        short8 a = *(const short8*)(Ah + arow * 1024 + ((kk * 64 + kbase) ^ sw));
        acc = __builtin_amdgcn_mfma_f32_16x16x32_bf16(a, uf[kk], acc, 0, 0, 0);
      }
    }
#pragma unroll
    for (int r = 0; r < 4; r++) {
      int row = ((lane >> 4) << 2) + r, col = lane & 15;
      gates[w][row][col] = acc[r] + biasv + bf2f(xgt[w][row][col]);
    }
    __syncthreads();

    {
      int row = tid >> 4, col = tid & 15;
      float gi = gates[0][row][col];
      float gf = gates[1][row][col];
      float gc = gates[2][row][col];
      float go = gates[3][row][col];
      float iv = 1.0f / (1.0f + __expf(-gi));
      float fv = 1.0f / (1.0f + __expf(-gf));
      float cd = tanhf(gc);
      float ov = 1.0f / (1.0f + __expf(-go));
      float cold = cst[row][col];
      float cn = fv * cold + iv * cd;
      float hn = ov * tanhf(cn);
      if (wid[(b0 + row) * T_SEQ + t] == 0) {
        cn = cold;
        unsigned short hp =
            *(const unsigned short*)(Ah + row * 1024 + (((j0 + col) * 2) ^ ((row & 7) << 4)));
        hn = bf2f(hp);
      }
      cst[row][col] = cn;
      hseq[((size_t)(b0 + row) * T_SEQ + t) * HID + j0 + col] = f2bf(hn);
    }

    if (t < T_SEQ - 1) {
      __threadfence();
      __syncthreads();
      if (tid == 0)
        __hip_atomic_store(&flags[bgrp * 32 + jblk], t + 1, __ATOMIC_RELEASE,
                           __HIP_MEMORY_SCOPE_AGENT);
      if (tid < 32) {
        while (__hip_atomic_load(&flags[bgrp * 32 + tid], __ATOMIC_ACQUIRE,
                                 __HIP_MEMORY_SCOPE_AGENT) <= t) {
          __builtin_amdgcn_s_sleep(1);
        }
      }
      __syncthreads();
    }
  }
}

// ---------- dense (512->96) + softmax, MFMA ----------
__global__ __launch_bounds__(256) void dense_softmax(const unsigned short* __restrict__ h2,
                                                     const unsigned short* __restrict__ Wdt,
                                                     const float* __restrict__ bd,
                                                     float* __restrict__ out) {
  int m0 = blockIdx.x * 64;
  int tid = threadIdx.x, lane = tid & 63, w = tid >> 6;
  __shared__ __align__(16) char As[64 * ASTR];
  __shared__ __align__(16) char Bs[96 * ASTR];
  floatx4 acc[6];
#pragma unroll
  for (int i = 0; i < 6; i++) acc[i] = (floatx4){0.f, 0.f, 0.f, 0.f};
  for (int k0 = 0; k0 < 512; k0 += 32) {
    {
      int row = tid >> 2, part = tid & 3;
      short8 v = *(const short8*)(h2 + (size_t)(m0 + row) * 512 + k0 + part * 8);
      *(short8*)(As + row * ASTR + part * 16) = v;
    }
    for (int u = tid; u < 96 * 4; u += 256) {
      int col = u >> 2, part = u & 3;
      short8 v = *(const short8*)(Wdt + (size_t)col * 512 + k0 + part * 8);
      *(short8*)(Bs + col * ASTR + part * 16) = v;
    }
    __syncthreads();
    int arow = w * 16 + (lane & 15);
    short8 a = *(const short8*)(As + arow * ASTR + (lane >> 4) * 16);
#pragma unroll
    for (int nc = 0; nc < 6; nc++) {
      int bcol = nc * 16 + (lane & 15);
      short8 b = *(const short8*)(Bs + bcol * ASTR + (lane >> 4) * 16);
      acc[nc] = __builtin_amdgcn_mfma_f32_16x16x32_bf16(a, b, acc[nc], 0, 0, 0);
    }
    __syncthreads();
  }
  float bv[6];
#pragma unroll
  for (int nc = 0; nc < 6; nc++) bv[nc] = bd[nc * 16 + (lane & 15)];
#pragma unroll
  for (int r = 0; r < 4; r++) {
    float v[6];
    float mx = -1e30f;
#pragma unroll
    for (int nc = 0; nc < 6; nc++) {
      v[nc] = acc[nc][r] + bv[nc];
      mx = fmaxf(mx, v[nc]);
    }
#pragma unroll
    for (int d = 1; d < 16; d <<= 1) mx = fmaxf(mx, __shfl_xor(mx, d));
    float s = 0.f;
#pragma unroll
    for (int nc = 0; nc < 6; nc++) {
      v[nc] = __expf(v[nc] - mx);
      s += v[nc];
    }
#pragma unroll
    for (int d = 1; d < 16; d <<= 1) s += __shfl_xor(s, d);
    float inv = 1.0f / s;
    int rr = m0 + w * 16 + ((lane >> 4) << 2) + r;
#pragma unroll
    for (int nc = 0; nc < 6; nc++) out[(size_t)rr * 96 + nc * 16 + (lane & 15)] = v[nc] * inv;
  }
}

extern "C" void kernel_launch(void* const* d_in, const int* in_sizes, int n_in,
                              void* d_out, int out_size, void* d_ws, size_t ws_size,
                              hipStream_t stream) {
  (void)in_sizes; (void)n_in; (void)out_size; (void)ws_size;
  const int* word_ids = (const int*)d_in[0];
  const int* pred = (const int*)d_in[1];
  const float* emb = (const float*)d_in[2];
  const float* W1 = (const float*)d_in[3];
  const float* U1 = (const float*)d_in[4];
  const float* b1 = (const float*)d_in[5];
  const float* W2 = (const float*)d_in[6];
  const float* U2 = (const float*)d_in[7];
  const float* b2 = (const float*)d_in[8];
  const float* Wd = (const float*)d_in[9];
  const float* bd = (const float*)d_in[10];
  float* out = (float*)d_out;

  char* p = (char*)d_ws;
  unsigned short* xg = (unsigned short*)p;  p += (size_t)32768 * 2048 * 2;
  unsigned short* h1 = (unsigned short*)p;  p += (size_t)32768 * 512 * 2;
  unsigned short* h2 = (unsigned short*)p;  p += (size_t)32768 * 512 * 2;
  unsigned short* Ut1 = (unsigned short*)p; p += (size_t)2048 * 512 * 2;
  unsigned short* Ut2 = (unsigned short*)p; p += (size_t)2048 * 512 * 2;
  unsigned short* Wt1 = (unsigned short*)p; p += (size_t)2048 * 320 * 2;
  unsigned short* Wt2 = (unsigned short*)p; p += (size_t)2048 * 512 * 2;
  unsigned short* Wdt = (unsigned short*)p; p += (size_t)96 * 512 * 2;
  int* flags = (int*)p;                     p += 2048;

  hipLaunchKernelGGL(init_flags, dim3(1), dim3(512), 0, stream, flags);
  hipLaunchKernelGGL(transpose_bf16, dim3(64, 16), dim3(256), 0, stream, U1, Ut1, 512, 2048, 512);
  hipLaunchKernelGGL(transpose_bf16, dim3(64, 16), dim3(256), 0, stream, U2, Ut2, 512, 2048, 512);
  hipLaunchKernelGGL(transpose_bf16, dim3(64, 10), dim3(256), 0, stream, W1, Wt1, 301, 2048, 320);
  hipLaunchKernelGGL(transpose_bf16, dim3(64, 16), dim3(256), 0, stream, W2, Wt2, 512, 2048, 512);
  hipLaunchKernelGGL(transpose_bf16, dim3(3, 16), dim3(256), 0, stream, Wd, Wdt, 512, 96, 512);

  hipLaunchKernelGGL((gemm_xg<true>), dim3(32, 512), dim3(256), 0, stream,
                     (const void*)emb, word_ids, pred, Wt1, xg, 320);
  hipLaunchKernelGGL(lstm_layer, dim3(256), dim3(256), 0, stream, xg, Ut1, b1, word_ids, h1, flags);
  hipLaunchKernelGGL((gemm_xg<false>), dim3(32, 512), dim3(256), 0, stream,
                     (const void*)h1, (const int*)nullptr, (const int*)nullptr, Wt2, xg, 512);
  hipLaunchKernelGGL(lstm_layer, dim3(256), dim3(256), 0, stream, xg, Ut2, b2, word_ids, h2,
                     flags + 256);
  hipLaunchKernelGGL(dense_softmax, dim3(512), dim3(256), 0, stream, h2, Wdt, bd, out);
}

// Round 3
// 1838.591 us; speedup vs baseline: 7.7559x; 7.7559x over previous
//
#include <hip/hip_runtime.h>
#include <hip/hip_bf16.h>

#define T_SEQ 256
#define HID 512
#define G4 2048
#define ASTR 80  // padded LDS row stride (bytes) for 64B rows: bijective, 2-way banks = free

typedef __attribute__((ext_vector_type(8))) short short8;
typedef __attribute__((ext_vector_type(4))) float floatx4;
typedef __attribute__((ext_vector_type(4))) int intx4;

__device__ inline unsigned short f2bf(float f) {
  union { __hip_bfloat16 h; unsigned short u; } cv;
  cv.h = __float2bfloat16(f);
  return cv.u;
}
__device__ inline float bf2f(unsigned short u) {
  union { unsigned short u; __hip_bfloat16 h; } cv;
  cv.u = u;
  return __bfloat162float(cv.h);
}
// fast sigmoid/tanh: v_exp + v_rcp (rel err ~1e-7, irrelevant vs bf16 storage)
__device__ inline float fsigmoid(float x) {
  return __builtin_amdgcn_rcpf(1.0f + __expf(-x));
}
__device__ inline float ftanh(float x) {
  float e = __expf(2.0f * x);
  return 1.0f - 2.0f * __builtin_amdgcn_rcpf(e + 1.0f);
}

// zero the barrier flags (both layers' regions)
__global__ void init_flags(int* flags) { flags[threadIdx.x] = 0; }

// ---------- transpose+convert: src [K][N] f32 -> dst [N][Kpad] bf16 (zero pad) ----------
__global__ __launch_bounds__(256) void transpose_bf16(const float* __restrict__ src,
                                                      unsigned short* __restrict__ dst,
                                                      int K, int N, int Kpad) {
  __shared__ float tile[32][33];
  int n0 = blockIdx.x * 32, k0 = blockIdx.y * 32;
  int tx = threadIdx.x & 31, ty = threadIdx.x >> 5;  // 32 x 8
#pragma unroll
  for (int i = 0; i < 32; i += 8) {
    int k = k0 + ty + i, n = n0 + tx;
    tile[ty + i][tx] = (k < K) ? src[(size_t)k * N + n] : 0.0f;
  }
  __syncthreads();
#pragma unroll
  for (int i = 0; i < 32; i += 8) {
    int n = n0 + ty + i, k = k0 + tx;
    dst[(size_t)n * Kpad + k] = f2bf(tile[tx][ty + i]);
  }
}

// ---------- bf16 MFMA GEMM: C[m][n] = sum_k A[m][k]*B[k][n]; Bt is [n][Kpad] bf16 ----------
// GATHER: A row m = [emb[wid[m]][0..299], predflag[m], 0 pad...]
template <bool GATHER>
__global__ __launch_bounds__(256) void gemm_xg(const void* __restrict__ Asrc,
                                               const int* __restrict__ wid,
                                               const int* __restrict__ pred,
                                               const unsigned short* __restrict__ Bt,
                                               unsigned short* __restrict__ C,
                                               int Kpad) {
  int n0 = blockIdx.x * 64, m0 = blockIdx.y * 64;
  int tid = threadIdx.x, lane = tid & 63, w = tid >> 6;
  int wr = w >> 1, wc = w & 1;
  __shared__ __align__(16) char As[64 * ASTR];
  __shared__ __align__(16) char Bs[64 * ASTR];
  __shared__ int wids[64];
  __shared__ float pf[64];
  if (GATHER) {
    if (tid < 64) {
      wids[tid] = wid[m0 + tid];
      pf[tid] = (float)pred[m0 + tid];
    }
    __syncthreads();
  }
  floatx4 acc[2][2];
#pragma unroll
  for (int a = 0; a < 2; a++)
#pragma unroll
    for (int b = 0; b < 2; b++) acc[a][b] = (floatx4){0.f, 0.f, 0.f, 0.f};

  int row = tid >> 2, part = tid & 3;
  for (int k0 = 0; k0 < Kpad; k0 += 32) {
    short8 av;
    if (GATHER) {
      const float* emb = (const float*)Asrc;
      int kb = k0 + part * 8;
      const float* erow = emb + (size_t)wids[row] * 300;
      float f[8];
      if (kb + 8 <= 300) {
        const float4* p4 = (const float4*)(erow + kb);
        float4 x0 = p4[0], x1 = p4[1];
        f[0] = x0.x; f[1] = x0.y; f[2] = x0.z; f[3] = x0.w;
        f[4] = x1.x; f[5] = x1.y; f[6] = x1.z; f[7] = x1.w;
      } else {
#pragma unroll
        for (int j = 0; j < 8; j++) {
          int k = kb + j;
          f[j] = (k < 300) ? erow[k] : ((k == 300) ? pf[row] : 0.0f);
        }
      }
      short8 v;
#pragma unroll
      for (int j = 0; j < 8; j++) v[j] = (short)f2bf(f[j]);
      av = v;
    } else {
      const unsigned short* A = (const unsigned short*)Asrc;
      av = *(const short8*)(A + (size_t)(m0 + row) * Kpad + k0 + part * 8);
    }
    *(short8*)(As + row * ASTR + part * 16) = av;
    short8 bv = *(const short8*)(Bt + (size_t)(n0 + row) * Kpad + k0 + part * 8);
    *(short8*)(Bs + row * ASTR + part * 16) = bv;
    __syncthreads();
    short8 afr[2], bfr[2];
#pragma unroll
    for (int mr = 0; mr < 2; mr++) {
      int arow = wr * 32 + mr * 16 + (lane & 15);
      afr[mr] = *(const short8*)(As + arow * ASTR + (lane >> 4) * 16);
    }
#pragma unroll
    for (int nc = 0; nc < 2; nc++) {
      int bcol = wc * 32 + nc * 16 + (lane & 15);
      bfr[nc] = *(const short8*)(Bs + bcol * ASTR + (lane >> 4) * 16);
    }
#pragma unroll
    for (int mr = 0; mr < 2; mr++)
#pragma unroll
      for (int nc = 0; nc < 2; nc++)
        acc[mr][nc] = __builtin_amdgcn_mfma_f32_16x16x32_bf16(afr[mr], bfr[nc], acc[mr][nc], 0, 0, 0);
    __syncthreads();
  }
#pragma unroll
  for (int mr = 0; mr < 2; mr++)
#pragma unroll
    for (int nc = 0; nc < 2; nc++)
#pragma unroll
      for (int r = 0; r < 4; r++) {
        int rr = m0 + wr * 32 + mr * 16 + ((lane >> 4) << 2) + r;
        int cc = n0 + wc * 32 + nc * 16 + (lane & 15);
        C[(size_t)rr * G4 + cc] = f2bf(acc[mr][nc][r]);
      }
}

// ---------- persistent masked-LSTM layer ----------
// grid = 256 blocks: bgrp = blk&7 (8 groups of 16 batch rows), jblk = blk>>3 (32 slices of 16 j)
// Cross-block h exchange via Infinity Cache using per-access sc0 sc1 ops ONLY —
// no __threadfence / acquire / release (those emit buffer_wbl2 / buffer_inv which
// write back + invalidate the whole XCD L2 every step: the round-2 27us/step pathology).
// Protocol: h stores sc0sc1 -> s_waitcnt vmcnt(0) -> barrier -> flag store sc0sc1;
// pollers: flag load sc0sc1 until > t, then h loads sc0sc1 (issue-after, so ordered).
__global__ __launch_bounds__(256, 1) void lstm_layer(const unsigned short* __restrict__ xg,
                                                     const unsigned short* __restrict__ Ut,
                                                     const float* __restrict__ bias,
                                                     const int* __restrict__ wid,
                                                     unsigned short* hseq,
                                                     int* flags) {
  int blk = blockIdx.x;
  int bgrp = blk & 7;
  int jblk = blk >> 3;
  int b0 = bgrp * 16;
  int j0 = jblk * 16;
  int tid = threadIdx.x, lane = tid & 63, w = tid >> 6;

  __shared__ __align__(16) char Ah[16 * 1024];  // h_prev bf16 [16 rows][512 k], XOR-swizzled
  __shared__ float gates[4][16][16];
  __shared__ float cst[16][16];
  __shared__ __align__(16) unsigned short xgt[4][16][16];

  // preload U fragments: wave w handles gate w, cols j0..j0+15
  short8 uf[16];
  int ucol = w * 512 + j0 + (lane & 15);
  {
    const unsigned short* up = Ut + (size_t)ucol * 512 + ((lane >> 4) * 8);
#pragma unroll
    for (int kk = 0; kk < 16; kk++) uf[kk] = *(const short8*)(up + kk * 32);
  }
  float biasv = bias[ucol];

  if (tid < 256) cst[tid >> 4][tid & 15] = 0.0f;
  {
    short8 z = {0, 0, 0, 0, 0, 0, 0, 0};
    for (int i = tid; i < 1024; i += 256) *(short8*)(Ah + i * 16) = z;
  }
  __syncthreads();

  // xg prefetch lane mapping (uint2 = 4 bf16 per thread per step)
  int xg_g = tid >> 6, xg_rw = (tid >> 2) & 15, xg_part = tid & 3;
  const uint2* xsrc0 = (const uint2*)(xg + ((size_t)(b0 + xg_rw) * T_SEQ + 0) * G4 +
                                      xg_g * 512 + j0 + xg_part * 4);
  uint2 xpf = *xsrc0;

  for (int t = 0; t < T_SEQ; t++) {
    if (t > 0) {
      // stage h(t-1): 64B/thread via 4x dwordx4, bypass L1+L2 (read Infinity Cache)
      int row = tid >> 4, c16 = tid & 15;
      const unsigned short* hp =
          hseq + ((size_t)(b0 + row) * T_SEQ + (t - 1)) * HID + c16 * 8;
      intx4 a0, a1, a2, a3;
      asm volatile(
          "global_load_dwordx4 %0, %4, off sc0 sc1\n\t"
          "global_load_dwordx4 %1, %4, off offset:256 sc0 sc1\n\t"
          "global_load_dwordx4 %2, %4, off offset:512 sc0 sc1\n\t"
          "global_load_dwordx4 %3, %4, off offset:768 sc0 sc1\n\t"
          "s_waitcnt vmcnt(0)"
          : "=&v"(a0), "=&v"(a1), "=&v"(a2), "=&v"(a3)
          : "v"(hp)
          : "memory");
      int sw = (row & 7) << 4;
      char* abase = Ah + row * 1024;
      *(short8*)(abase + (((c16 + 0) * 16) ^ sw)) = *(short8*)&a0;
      *(short8*)(abase + (((c16 + 16) * 16) ^ sw)) = *(short8*)&a1;
      *(short8*)(abase + (((c16 + 32) * 16) ^ sw)) = *(short8*)&a2;
      *(short8*)(abase + (((c16 + 48) * 16) ^ sw)) = *(short8*)&a3;
    }
    // consume prefetched xg(t), issue prefetch for xg(t+1)
    *(uint2*)(&xgt[xg_g][xg_rw][xg_part * 4]) = xpf;
    if (t + 1 < T_SEQ) {
      const uint2* xsrc = (const uint2*)(xg + ((size_t)(b0 + xg_rw) * T_SEQ + (t + 1)) * G4 +
                                         xg_g * 512 + j0 + xg_part * 4);
      xpf = *xsrc;
    }
    __syncthreads();

    floatx4 acc = (floatx4){0.f, 0.f, 0.f, 0.f};
    {
      int arow = lane & 15;
      int kbase = (lane >> 4) * 16;
      int sw = (arow & 7) << 4;
#pragma unroll
      for (int kk = 0; kk < 16; kk++) {
        short8 a = *(const short8*)(Ah + arow * 1024 + ((kk * 64 + kbase) ^ sw));
        acc = __builtin_amdgcn_mfma_f32_16x16x32_bf16(a, uf[kk], acc, 0, 0, 0);
      }
    }
#pragma unroll
    for (int r = 0; r < 4; r++) {
      int row = ((lane >> 4) << 2) + r, col = lane & 15;
      gates[w][row][col] = acc[r] + biasv + bf2f(xgt[w][row][col]);
    }
    __syncthreads();

    {
      int row = tid >> 4, col = tid & 15;
      float gi = gates[0][row][col];
      float gf = gates[1][row][col];
      float gc = gates[2][row][col];
      float go = gates[3][row][col];
      float iv = fsigmoid(gi);
      float fv = fsigmoid(gf);
      float cd = ftanh(gc);
      float ov = fsigmoid(go);
      float cold = cst[row][col];
      float cn = fv * cold + iv * cd;
      float hn = ov * ftanh(cn);
      if (wid[(b0 + row) * T_SEQ + t] == 0) {
        cn = cold;
        unsigned short hp =
            *(const unsigned short*)(Ah + row * 1024 + (((j0 + col) * 2) ^ ((row & 7) << 4)));
        hn = bf2f(hp);
      }
      cst[row][col] = cn;
      unsigned int hv = f2bf(hn);
      unsigned short* hdst = hseq + ((size_t)(b0 + row) * T_SEQ + t) * HID + j0 + col;
      asm volatile("global_store_short %0, %1, off sc0 sc1" ::"v"(hdst), "v"(hv) : "memory");
    }

    if (t < T_SEQ - 1) {
      // all h stores acked at IC before anyone signals
      asm volatile("s_waitcnt vmcnt(0)" ::: "memory");
      __syncthreads();
      if (tid == 0) {
        int val = t + 1;
        int* fdst = &flags[bgrp * 32 + jblk];
        asm volatile("global_store_dword %0, %1, off sc0 sc1" ::"v"(fdst), "v"(val) : "memory");
      }
      if (tid < 32) {
        const int* fp = &flags[bgrp * 32 + tid];
        while (true) {
          int v;
          asm volatile("global_load_dword %0, %1, off sc0 sc1\n\ts_waitcnt vmcnt(0)"
                       : "=v"(v)
                       : "v"(fp)
                       : "memory");
          if (v > t) break;
          __builtin_amdgcn_s_sleep(2);
        }
      }
      __syncthreads();
    }
  }
}

// ---------- dense (512->96) + softmax, MFMA ----------
__global__ __launch_bounds__(256) void dense_softmax(const unsigned short* __restrict__ h2,
                                                     const unsigned short* __restrict__ Wdt,
                                                     const float* __restrict__ bd,
                                                     float* __restrict__ out) {
  int m0 = blockIdx.x * 64;
  int tid = threadIdx.x, lane = tid & 63, w = tid >> 6;
  __shared__ __align__(16) char As[64 * ASTR];
  __shared__ __align__(16) char Bs[96 * ASTR];
  floatx4 acc[6];
#pragma unroll
  for (int i = 0; i < 6; i++) acc[i] = (floatx4){0.f, 0.f, 0.f, 0.f};
  for (int k0 = 0; k0 < 512; k0 += 32) {
    {
      int row = tid >> 2, part = tid & 3;
      short8 v = *(const short8*)(h2 + (size_t)(m0 + row) * 512 + k0 + part * 8);
      *(short8*)(As + row * ASTR + part * 16) = v;
    }
    for (int u = tid; u < 96 * 4; u += 256) {
      int col = u >> 2, part = u & 3;
      short8 v = *(const short8*)(Wdt + (size_t)col * 512 + k0 + part * 8);
      *(short8*)(Bs + col * ASTR + part * 16) = v;
    }
    __syncthreads();
    int arow = w * 16 + (lane & 15);
    short8 a = *(const short8*)(As + arow * ASTR + (lane >> 4) * 16);
#pragma unroll
    for (int nc = 0; nc < 6; nc++) {
      int bcol = nc * 16 + (lane & 15);
      short8 b = *(const short8*)(Bs + bcol * ASTR + (lane >> 4) * 16);
      acc[nc] = __builtin_amdgcn_mfma_f32_16x16x32_bf16(a, b, acc[nc], 0, 0, 0);
    }
    __syncthreads();
  }
  float bv[6];
#pragma unroll
  for (int nc = 0; nc < 6; nc++) bv[nc] = bd[nc * 16 + (lane & 15)];
#pragma unroll
  for (int r = 0; r < 4; r++) {
    float v[6];
    float mx = -1e30f;
#pragma unroll
    for (int nc = 0; nc < 6; nc++) {
      v[nc] = acc[nc][r] + bv[nc];
      mx = fmaxf(mx, v[nc]);
    }
#pragma unroll
    for (int d = 1; d < 16; d <<= 1) mx = fmaxf(mx, __shfl_xor(mx, d));
    float s = 0.f;
#pragma unroll
    for (int nc = 0; nc < 6; nc++) {
      v[nc] = __expf(v[nc] - mx);
      s += v[nc];
    }
#pragma unroll
    for (int d = 1; d < 16; d <<= 1) s += __shfl_xor(s, d);
    float inv = 1.0f / s;
    int rr = m0 + w * 16 + ((lane >> 4) << 2) + r;
#pragma unroll
    for (int nc = 0; nc < 6; nc++) out[(size_t)rr * 96 + nc * 16 + (lane & 15)] = v[nc] * inv;
  }
}

extern "C" void kernel_launch(void* const* d_in, const int* in_sizes, int n_in,
                              void* d_out, int out_size, void* d_ws, size_t ws_size,
                              hipStream_t stream) {
  (void)in_sizes; (void)n_in; (void)out_size; (void)ws_size;
  const int* word_ids = (const int*)d_in[0];
  const int* pred = (const int*)d_in[1];
  const float* emb = (const float*)d_in[2];
  const float* W1 = (const float*)d_in[3];
  const float* U1 = (const float*)d_in[4];
  const float* b1 = (const float*)d_in[5];
  const float* W2 = (const float*)d_in[6];
  const float* U2 = (const float*)d_in[7];
  const float* b2 = (const float*)d_in[8];
  const float* Wd = (const float*)d_in[9];
  const float* bd = (const float*)d_in[10];
  float* out = (float*)d_out;

  char* p = (char*)d_ws;
  unsigned short* xg = (unsigned short*)p;  p += (size_t)32768 * 2048 * 2;
  unsigned short* h1 = (unsigned short*)p;  p += (size_t)32768 * 512 * 2;
  unsigned short* h2 = (unsigned short*)p;  p += (size_t)32768 * 512 * 2;
  unsigned short* Ut1 = (unsigned short*)p; p += (size_t)2048 * 512 * 2;
  unsigned short* Ut2 = (unsigned short*)p; p += (size_t)2048 * 512 * 2;
  unsigned short* Wt1 = (unsigned short*)p; p += (size_t)2048 * 320 * 2;
  unsigned short* Wt2 = (unsigned short*)p; p += (size_t)2048 * 512 * 2;
  unsigned short* Wdt = (unsigned short*)p; p += (size_t)96 * 512 * 2;
  int* flags = (int*)p;                     p += 2048;

  hipLaunchKernelGGL(init_flags, dim3(1), dim3(512), 0, stream, flags);
  hipLaunchKernelGGL(transpose_bf16, dim3(64, 16), dim3(256), 0, stream, U1, Ut1, 512, 2048, 512);
  hipLaunchKernelGGL(transpose_bf16, dim3(64, 16), dim3(256), 0, stream, U2, Ut2, 512, 2048, 512);
  hipLaunchKernelGGL(transpose_bf16, dim3(64, 10), dim3(256), 0, stream, W1, Wt1, 301, 2048, 320);
  hipLaunchKernelGGL(transpose_bf16, dim3(64, 16), dim3(256), 0, stream, W2, Wt2, 512, 2048, 512);
  hipLaunchKernelGGL(transpose_bf16, dim3(3, 16), dim3(256), 0, stream, Wd, Wdt, 512, 96, 512);

  hipLaunchKernelGGL((gemm_xg<true>), dim3(32, 512), dim3(256), 0, stream,
                     (const void*)emb, word_ids, pred, Wt1, xg, 320);
  hipLaunchKernelGGL(lstm_layer, dim3(256), dim3(256), 0, stream, xg, Ut1, b1, word_ids, h1, flags);
  hipLaunchKernelGGL((gemm_xg<false>), dim3(32, 512), dim3(256), 0, stream,
                     (const void*)h1, (const int*)nullptr, (const int*)nullptr, Wt2, xg, 512);
  hipLaunchKernelGGL(lstm_layer, dim3(256), dim3(256), 0, stream, xg, Ut2, b2, word_ids, h2,
                     flags + 256);
  hipLaunchKernelGGL(dense_softmax, dim3(512), dim3(256), 0, stream, h2, Wdt, bd, out);
}

// Round 4
// 1765.313 us; speedup vs baseline: 8.0779x; 1.0415x over previous
//
#include <hip/hip_runtime.h>
#include <hip/hip_bf16.h>

#define T_SEQ 256
#define HID 512
#define G4 2048
#define ASTR 80  // padded LDS row stride (bytes) for 64B rows: bijective, 2-way banks = free

typedef __attribute__((ext_vector_type(8))) short short8;
typedef __attribute__((ext_vector_type(4))) float floatx4;
typedef __attribute__((ext_vector_type(4))) int intx4;

__device__ inline unsigned short f2bf(float f) {
  union { __hip_bfloat16 h; unsigned short u; } cv;
  cv.h = __float2bfloat16(f);
  return cv.u;
}
__device__ inline float bf2f(unsigned short u) {
  union { unsigned short u; __hip_bfloat16 h; } cv;
  cv.u = u;
  return __bfloat162float(cv.h);
}
__device__ inline float fsigmoid(float x) {
  return __builtin_amdgcn_rcpf(1.0f + __expf(-x));
}
__device__ inline float ftanh(float x) {
  float e = __expf(2.0f * x);
  return 1.0f - 2.0f * __builtin_amdgcn_rcpf(e + 1.0f);
}

// ---------- transpose+convert: src [K][N] f32 -> dst [N][Kpad] bf16 (zero pad) ----------
__global__ __launch_bounds__(256) void transpose_bf16(const float* __restrict__ src,
                                                      unsigned short* __restrict__ dst,
                                                      int K, int N, int Kpad) {
  __shared__ float tile[32][33];
  int n0 = blockIdx.x * 32, k0 = blockIdx.y * 32;
  int tx = threadIdx.x & 31, ty = threadIdx.x >> 5;  // 32 x 8
#pragma unroll
  for (int i = 0; i < 32; i += 8) {
    int k = k0 + ty + i, n = n0 + tx;
    tile[ty + i][tx] = (k < K) ? src[(size_t)k * N + n] : 0.0f;
  }
  __syncthreads();
#pragma unroll
  for (int i = 0; i < 32; i += 8) {
    int n = n0 + ty + i, k = k0 + tx;
    dst[(size_t)n * Kpad + k] = f2bf(tile[tx][ty + i]);
  }
}

// ---------- bf16 MFMA GEMM (gather variant used for xg1 only) ----------
template <bool GATHER>
__global__ __launch_bounds__(256) void gemm_xg(const void* __restrict__ Asrc,
                                               const int* __restrict__ wid,
                                               const int* __restrict__ pred,
                                               const unsigned short* __restrict__ Bt,
                                               unsigned short* __restrict__ C,
                                               int Kpad) {
  int n0 = blockIdx.x * 64, m0 = blockIdx.y * 64;
  int tid = threadIdx.x, lane = tid & 63, w = tid >> 6;
  int wr = w >> 1, wc = w & 1;
  __shared__ __align__(16) char As[64 * ASTR];
  __shared__ __align__(16) char Bs[64 * ASTR];
  __shared__ int wids[64];
  __shared__ float pf[64];
  if (GATHER) {
    if (tid < 64) {
      wids[tid] = wid[m0 + tid];
      pf[tid] = (float)pred[m0 + tid];
    }
    __syncthreads();
  }
  floatx4 acc[2][2];
#pragma unroll
  for (int a = 0; a < 2; a++)
#pragma unroll
    for (int b = 0; b < 2; b++) acc[a][b] = (floatx4){0.f, 0.f, 0.f, 0.f};

  int row = tid >> 2, part = tid & 3;
  for (int k0 = 0; k0 < Kpad; k0 += 32) {
    short8 av;
    if (GATHER) {
      const float* emb = (const float*)Asrc;
      int kb = k0 + part * 8;
      const float* erow = emb + (size_t)wids[row] * 300;
      float f[8];
      if (kb + 8 <= 300) {
        const float4* p4 = (const float4*)(erow + kb);
        float4 x0 = p4[0], x1 = p4[1];
        f[0] = x0.x; f[1] = x0.y; f[2] = x0.z; f[3] = x0.w;
        f[4] = x1.x; f[5] = x1.y; f[6] = x1.z; f[7] = x1.w;
      } else {
#pragma unroll
        for (int j = 0; j < 8; j++) {
          int k = kb + j;
          f[j] = (k < 300) ? erow[k] : ((k == 300) ? pf[row] : 0.0f);
        }
      }
      short8 v;
#pragma unroll
      for (int j = 0; j < 8; j++) v[j] = (short)f2bf(f[j]);
      av = v;
    } else {
      const unsigned short* A = (const unsigned short*)Asrc;
      av = *(const short8*)(A + (size_t)(m0 + row) * Kpad + k0 + part * 8);
    }
    *(short8*)(As + row * ASTR + part * 16) = av;
    short8 bv = *(const short8*)(Bt + (size_t)(n0 + row) * Kpad + k0 + part * 8);
    *(short8*)(Bs + row * ASTR + part * 16) = bv;
    __syncthreads();
    short8 afr[2], bfr[2];
#pragma unroll
    for (int mr = 0; mr < 2; mr++) {
      int arow = wr * 32 + mr * 16 + (lane & 15);
      afr[mr] = *(const short8*)(As + arow * ASTR + (lane >> 4) * 16);
    }
#pragma unroll
    for (int nc = 0; nc < 2; nc++) {
      int bcol = wc * 32 + nc * 16 + (lane & 15);
      bfr[nc] = *(const short8*)(Bs + bcol * ASTR + (lane >> 4) * 16);
    }
#pragma unroll
    for (int mr = 0; mr < 2; mr++)
#pragma unroll
      for (int nc = 0; nc < 2; nc++)
        acc[mr][nc] = __builtin_amdgcn_mfma_f32_16x16x32_bf16(afr[mr], bfr[nc], acc[mr][nc], 0, 0, 0);
    __syncthreads();
  }
#pragma unroll
  for (int mr = 0; mr < 2; mr++)
#pragma unroll
    for (int nc = 0; nc < 2; nc++)
#pragma unroll
      for (int r = 0; r < 4; r++) {
        int rr = m0 + wr * 32 + mr * 16 + ((lane >> 4) << 2) + r;
        int cc = n0 + wc * 32 + nc * 16 + (lane & 15);
        C[(size_t)rr * G4 + cc] = f2bf(acc[mr][nc][r]);
      }
}

// ---------- tagged-exchange staging ----------
// Each thread owns 32 h-elements of one batch row: granule i (0..7) = 4 tagged u32 at
// elems 8*c16 + 128*(i>>1) + 4*(i&1). A granule is valid when all 4 high-16 tags == want.
// Valid granules are untagged (low 16 = bf16) and written to the swizzled LDS A-tile.
// Data and synchronization arrive in the same load: ~1 IC round trip total.
__device__ __forceinline__ void stage_tagged(const unsigned int* rowbase, unsigned want,
                                             char* AhRow, int sw, int c16) {
  unsigned done = 0;
  while (done != 0xFFu) {
    intx4 v[8];
#pragma unroll
    for (int i = 0; i < 8; i++) {
      if (!(done & (1u << i))) {
        const unsigned int* p = rowbase + 8 * c16 + 128 * (i >> 1) + 4 * (i & 1);
        asm volatile("global_load_dwordx4 %0, %1, off sc0 sc1" : "=v"(v[i]) : "v"(p) : "memory");
      }
    }
    asm volatile("s_waitcnt vmcnt(0)" ::: "memory");
#pragma unroll
    for (int i = 0; i < 8; i++) {
      if (!(done & (1u << i))) {
        intx4 a = v[i];
        unsigned u0 = (unsigned)a.x, u1 = (unsigned)a.y, u2 = (unsigned)a.z, u3 = (unsigned)a.w;
        bool ok = ((u0 >> 16) == want) & ((u1 >> 16) == want) & ((u2 >> 16) == want) &
                  ((u3 >> 16) == want);
        if (ok) {
          unsigned lo = (u0 & 0xffffu) | (u1 << 16);
          unsigned hi = (u2 & 0xffffu) | (u3 << 16);
          int s = c16 + 16 * (i >> 1);
          uint2 pp; pp.x = lo; pp.y = hi;
          *(uint2*)(AhRow + ((s * 16) ^ sw) + (i & 1) * 8) = pp;
          done |= (1u << i);
        }
      }
    }
    if (done != 0xFFu) __builtin_amdgcn_s_sleep(1);
  }
}

// ---------- fused persistent dual-layer masked LSTM ----------
// blocks 0..255: layer1 (bgrp=blk&7, jblk=blk>>3). blocks 256..511: layer2.
// layer1: g1 = xg1(t) + h1(t-1)@U1 + b1 ; publishes h1(t) to full-seq tagged h1ex (64MB).
// layer2: g2 = h1(t)@W2 + h2(t-1)@U2 + b2 ; h2 recurrence via depth-2 tagged ring h2ex;
//         also writes bf16 h2seq for the dense head. gemm2 dispatch eliminated.
// Full-seq h1ex => layer1 never waits on layer2; worst-case degrades to serial (no deadlock).
__global__ __launch_bounds__(256, 2) void lstm_fused(
    const unsigned short* __restrict__ xg1,
    const unsigned short* __restrict__ Ut1, const float* __restrict__ b1,
    const unsigned short* __restrict__ Wt2, const unsigned short* __restrict__ Ut2,
    const float* __restrict__ b2, const int* __restrict__ wid,
    unsigned int* h1ex, unsigned int* h2ex, unsigned short* h2seq) {
  const int blk = blockIdx.x;
  const bool L2B = blk >= 256;
  const int lblk = L2B ? blk - 256 : blk;
  const int bgrp = lblk & 7, jblk = lblk >> 3;
  const int b0 = bgrp * 16, j0 = jblk * 16;
  const int tid = threadIdx.x, lane = tid & 63, w = tid >> 6;

  __shared__ __align__(16) char AhA[16 * 1024];  // L1: h1(t-1); L2: h1(t)
  __shared__ __align__(16) char AhB[16 * 1024];  // L2: h2(t-1)
  __shared__ float gates[4][16][16];
  __shared__ float cst[16][16];
  __shared__ __align__(16) unsigned short xgt[4][16][16];

  const int row = tid >> 4, c16 = tid & 15;  // staging + activation row mapping
  const int sw = (row & 7) << 4;
  char* AhRowA = AhA + row * 1024;
  char* AhRowB = AhB + row * 1024;
  const int ucol = w * 512 + j0 + (lane & 15);
  const int* widp = wid + (size_t)(b0 + row) * T_SEQ;

  if (!L2B) {
    // ---------------- layer 1 ----------------
    short8 uf[16];
    {
      const unsigned short* up = Ut1 + (size_t)ucol * 512 + ((lane >> 4) * 8);
#pragma unroll
      for (int kk = 0; kk < 16; kk++) uf[kk] = *(const short8*)(up + kk * 32);
    }
    float biasv = b1[ucol];
    cst[row][c16] = 0.0f;
    {
      short8 z = {0, 0, 0, 0, 0, 0, 0, 0};
      for (int i = tid; i < 1024; i += 256) *(short8*)(AhA + i * 16) = z;
    }
    __syncthreads();

    int xg_g = tid >> 6, xg_rw = (tid >> 2) & 15, xg_part = tid & 3;
    uint2 xpf = *(const uint2*)(xg1 + ((size_t)(b0 + xg_rw) * T_SEQ + 0) * G4 + xg_g * 512 +
                                j0 + xg_part * 4);
    int mcur = widp[0];

    for (int t = 0; t < T_SEQ; t++) {
      if (t > 0)
        stage_tagged(h1ex + ((size_t)(t - 1) * 128 + b0 + row) * 512, (unsigned)t, AhRowA, sw, c16);
      *(uint2*)(&xgt[xg_g][xg_rw][xg_part * 4]) = xpf;
      if (t + 1 < T_SEQ)
        xpf = *(const uint2*)(xg1 + ((size_t)(b0 + xg_rw) * T_SEQ + (t + 1)) * G4 + xg_g * 512 +
                              j0 + xg_part * 4);
      int mnext = (t + 1 < T_SEQ) ? widp[t + 1] : 0;
      __syncthreads();

      floatx4 acc = (floatx4){0.f, 0.f, 0.f, 0.f};
      {
        int frow = lane & 15, kbase = (lane >> 4) * 16, fsw = (frow & 7) << 4;
#pragma unroll
        for (int kk = 0; kk < 16; kk++) {
          short8 a = *(const short8*)(AhA + frow * 1024 + ((kk * 64 + kbase) ^ fsw));
          acc = __builtin_amdgcn_mfma_f32_16x16x32_bf16(a, uf[kk], acc, 0, 0, 0);
        }
      }
#pragma unroll
      for (int r = 0; r < 4; r++) {
        int grow = ((lane >> 4) << 2) + r, gcol = lane & 15;
        gates[w][grow][gcol] = acc[r] + biasv + bf2f(xgt[w][grow][gcol]);
      }
      __syncthreads();

      {
        float gi = gates[0][row][c16], gf = gates[1][row][c16];
        float gc = gates[2][row][c16], go = gates[3][row][c16];
        float iv = fsigmoid(gi), fv = fsigmoid(gf), cd = ftanh(gc), ov = fsigmoid(go);
        float cold = cst[row][c16];
        float cn = fv * cold + iv * cd;
        float hn = ov * ftanh(cn);
        if (mcur == 0) {
          cn = cold;
          unsigned short hp =
              *(const unsigned short*)(AhRowA + (((j0 + c16) * 2) ^ sw));
          hn = bf2f(hp);
        }
        cst[row][c16] = cn;
        unsigned tagged = ((unsigned)(t + 1) << 16) | f2bf(hn);
        unsigned int* dst = h1ex + ((size_t)t * 128 + b0 + row) * 512 + j0 + c16;
        asm volatile("global_store_dword %0, %1, off sc0 sc1" ::"v"(dst), "v"(tagged) : "memory");
      }
      mcur = mnext;
      __syncthreads();
    }
  } else {
    // ---------------- layer 2 (+ folded gemm2) ----------------
    short8 wf[16], uf[16];
    {
      const unsigned short* pA = Wt2 + (size_t)ucol * 512 + ((lane >> 4) * 8);
      const unsigned short* pB = Ut2 + (size_t)ucol * 512 + ((lane >> 4) * 8);
#pragma unroll
      for (int kk = 0; kk < 16; kk++) {
        wf[kk] = *(const short8*)(pA + kk * 32);
        uf[kk] = *(const short8*)(pB + kk * 32);
      }
    }
    float biasv = b2[ucol];
    cst[row][c16] = 0.0f;
    {
      short8 z = {0, 0, 0, 0, 0, 0, 0, 0};
      for (int i = tid; i < 1024; i += 256) *(short8*)(AhB + i * 16) = z;
    }
    __syncthreads();

    int mcur = widp[0];

    for (int t = 0; t < T_SEQ; t++) {
      // h1(t) from layer1 (full-seq tagged buffer)
      stage_tagged(h1ex + ((size_t)t * 128 + b0 + row) * 512, (unsigned)(t + 1), AhRowA, sw, c16);
      int mnext = (t + 1 < T_SEQ) ? widp[t + 1] : 0;
      __syncthreads();

      floatx4 acc = (floatx4){0.f, 0.f, 0.f, 0.f};
      {
        int frow = lane & 15, kbase = (lane >> 4) * 16, fsw = (frow & 7) << 4;
#pragma unroll
        for (int kk = 0; kk < 16; kk++) {
          short8 a = *(const short8*)(AhA + frow * 1024 + ((kk * 64 + kbase) ^ fsw));
          acc = __builtin_amdgcn_mfma_f32_16x16x32_bf16(a, wf[kk], acc, 0, 0, 0);
        }
      }
      // h2(t-1) from depth-2 ring (own group, lockstep => D=2 safe); overlaps W2 MFMAs
      if (t > 0)
        stage_tagged(h2ex + ((size_t)((t - 1) & 1) * 128 + b0 + row) * 512, (unsigned)t, AhRowB,
                     sw, c16);
      __syncthreads();
      {
        int frow = lane & 15, kbase = (lane >> 4) * 16, fsw = (frow & 7) << 4;
#pragma unroll
        for (int kk = 0; kk < 16; kk++) {
          short8 a = *(const short8*)(AhB + frow * 1024 + ((kk * 64 + kbase) ^ fsw));
          acc = __builtin_amdgcn_mfma_f32_16x16x32_bf16(a, uf[kk], acc, 0, 0, 0);
        }
      }
#pragma unroll
      for (int r = 0; r < 4; r++) {
        int grow = ((lane >> 4) << 2) + r, gcol = lane & 15;
        gates[w][grow][gcol] = acc[r] + biasv;
      }
      __syncthreads();

      {
        float gi = gates[0][row][c16], gf = gates[1][row][c16];
        float gc = gates[2][row][c16], go = gates[3][row][c16];
        float iv = fsigmoid(gi), fv = fsigmoid(gf), cd = ftanh(gc), ov = fsigmoid(go);
        float cold = cst[row][c16];
        float cn = fv * cold + iv * cd;
        float hn = ov * ftanh(cn);
        if (mcur == 0) {
          cn = cold;
          unsigned short hp =
              *(const unsigned short*)(AhRowB + (((j0 + c16) * 2) ^ sw));
          hn = bf2f(hp);
        }
        cst[row][c16] = cn;
        unsigned short hb = f2bf(hn);
        unsigned tagged = ((unsigned)(t + 1) << 16) | hb;
        unsigned int* dst = h2ex + ((size_t)(t & 1) * 128 + b0 + row) * 512 + j0 + c16;
        asm volatile("global_store_dword %0, %1, off sc0 sc1" ::"v"(dst), "v"(tagged) : "memory");
        h2seq[((size_t)(b0 + row) * T_SEQ + t) * HID + j0 + c16] = hb;
      }
      mcur = mnext;
      __syncthreads();
    }
  }
}

// ---------- dense (512->96) + softmax, MFMA ----------
__global__ __launch_bounds__(256) void dense_softmax(const unsigned short* __restrict__ h2,
                                                     const unsigned short* __restrict__ Wdt,
                                                     const float* __restrict__ bd,
                                                     float* __restrict__ out) {
  int m0 = blockIdx.x * 64;
  int tid = threadIdx.x, lane = tid & 63, w = tid >> 6;
  __shared__ __align__(16) char As[64 * ASTR];
  __shared__ __align__(16) char Bs[96 * ASTR];
  floatx4 acc[6];
#pragma unroll
  for (int i = 0; i < 6; i++) acc[i] = (floatx4){0.f, 0.f, 0.f, 0.f};
  for (int k0 = 0; k0 < 512; k0 += 32) {
    {
      int row = tid >> 2, part = tid & 3;
      short8 v = *(const short8*)(h2 + (size_t)(m0 + row) * 512 + k0 + part * 8);
      *(short8*)(As + row * ASTR + part * 16) = v;
    }
    for (int u = tid; u < 96 * 4; u += 256) {
      int col = u >> 2, part = u & 3;
      short8 v = *(const short8*)(Wdt + (size_t)col * 512 + k0 + part * 8);
      *(short8*)(Bs + col * ASTR + part * 16) = v;
    }
    __syncthreads();
    int arow = w * 16 + (lane & 15);
    short8 a = *(const short8*)(As + arow * ASTR + (lane >> 4) * 16);
#pragma unroll
    for (int nc = 0; nc < 6; nc++) {
      int bcol = nc * 16 + (lane & 15);
      short8 b = *(const short8*)(Bs + bcol * ASTR + (lane >> 4) * 16);
      acc[nc] = __builtin_amdgcn_mfma_f32_16x16x32_bf16(a, b, acc[nc], 0, 0, 0);
    }
    __syncthreads();
  }
  float bv[6];
#pragma unroll
  for (int nc = 0; nc < 6; nc++) bv[nc] = bd[nc * 16 + (lane & 15)];
#pragma unroll
  for (int r = 0; r < 4; r++) {
    float v[6];
    float mx = -1e30f;
#pragma unroll
    for (int nc = 0; nc < 6; nc++) {
      v[nc] = acc[nc][r] + bv[nc];
      mx = fmaxf(mx, v[nc]);
    }
#pragma unroll
    for (int d = 1; d < 16; d <<= 1) mx = fmaxf(mx, __shfl_xor(mx, d));
    float s = 0.f;
#pragma unroll
    for (int nc = 0; nc < 6; nc++) {
      v[nc] = __expf(v[nc] - mx);
      s += v[nc];
    }
#pragma unroll
    for (int d = 1; d < 16; d <<= 1) s += __shfl_xor(s, d);
    float inv = 1.0f / s;
    int rr = m0 + w * 16 + ((lane >> 4) << 2) + r;
#pragma unroll
    for (int nc = 0; nc < 6; nc++) out[(size_t)rr * 96 + nc * 16 + (lane & 15)] = v[nc] * inv;
  }
}

extern "C" void kernel_launch(void* const* d_in, const int* in_sizes, int n_in,
                              void* d_out, int out_size, void* d_ws, size_t ws_size,
                              hipStream_t stream) {
  (void)in_sizes; (void)n_in; (void)out_size; (void)ws_size;
  const int* word_ids = (const int*)d_in[0];
  const int* pred = (const int*)d_in[1];
  const float* emb = (const float*)d_in[2];
  const float* W1 = (const float*)d_in[3];
  const float* U1 = (const float*)d_in[4];
  const float* b1 = (const float*)d_in[5];
  const float* W2 = (const float*)d_in[6];
  const float* U2 = (const float*)d_in[7];
  const float* b2 = (const float*)d_in[8];
  const float* Wd = (const float*)d_in[9];
  const float* bd = (const float*)d_in[10];
  float* out = (float*)d_out;

  char* p = (char*)d_ws;
  unsigned short* xg = (unsigned short*)p;   p += (size_t)32768 * 2048 * 2;      // 128MB
  unsigned short* h2s = (unsigned short*)p;  p += (size_t)32768 * 512 * 2;       // 32MB
  unsigned int* h1ex = (unsigned int*)p;     p += (size_t)T_SEQ * 128 * 512 * 4; // 64MB
  unsigned int* h2ex = (unsigned int*)p;     p += (size_t)2 * 128 * 512 * 4;     // 512KB
  unsigned short* Ut1 = (unsigned short*)p;  p += (size_t)2048 * 512 * 2;
  unsigned short* Ut2 = (unsigned short*)p;  p += (size_t)2048 * 512 * 2;
  unsigned short* Wt1 = (unsigned short*)p;  p += (size_t)2048 * 320 * 2;
  unsigned short* Wt2 = (unsigned short*)p;  p += (size_t)2048 * 512 * 2;
  unsigned short* Wdt = (unsigned short*)p;  p += (size_t)96 * 512 * 2;

  // clear h1ex tags every launch: no reliance on cross-call buffer state
  hipMemsetAsync(h1ex, 0, (size_t)T_SEQ * 128 * 512 * 4, stream);

  hipLaunchKernelGGL(transpose_bf16, dim3(64, 16), dim3(256), 0, stream, U1, Ut1, 512, 2048, 512);
  hipLaunchKernelGGL(transpose_bf16, dim3(64, 16), dim3(256), 0, stream, U2, Ut2, 512, 2048, 512);
  hipLaunchKernelGGL(transpose_bf16, dim3(64, 10), dim3(256), 0, stream, W1, Wt1, 301, 2048, 320);
  hipLaunchKernelGGL(transpose_bf16, dim3(64, 16), dim3(256), 0, stream, W2, Wt2, 512, 2048, 512);
  hipLaunchKernelGGL(transpose_bf16, dim3(3, 16), dim3(256), 0, stream, Wd, Wdt, 512, 96, 512);

  hipLaunchKernelGGL((gemm_xg<true>), dim3(32, 512), dim3(256), 0, stream,
                     (const void*)emb, word_ids, pred, Wt1, xg, 320);
  hipLaunchKernelGGL(lstm_fused, dim3(512), dim3(256), 0, stream,
                     xg, Ut1, b1, Wt2, Ut2, b2, word_ids, h1ex, h2ex, h2s);
  hipLaunchKernelGGL(dense_softmax, dim3(512), dim3(256), 0, stream, h2s, Wdt, bd, out);
}

// Round 5
// 1707.468 us; speedup vs baseline: 8.3515x; 1.0339x over previous
//
#include <hip/hip_runtime.h>
#include <hip/hip_bf16.h>

#define T_SEQ 256
#define HID 512
#define G4 2048
#define ASTR 80  // padded LDS row stride (bytes) for 64B rows in GEMM kernels

typedef __attribute__((ext_vector_type(8))) short short8;
typedef __attribute__((ext_vector_type(4))) float floatx4;
typedef __attribute__((ext_vector_type(4))) int intx4;

__device__ inline unsigned short f2bf(float f) {
  union { __hip_bfloat16 h; unsigned short u; } cv;
  cv.h = __float2bfloat16(f);
  return cv.u;
}
__device__ inline float bf2f(unsigned short u) {
  union { unsigned short u; __hip_bfloat16 h; } cv;
  cv.u = u;
  return __bfloat162float(cv.h);
}
__device__ inline float fsigmoid(float x) {
  return __builtin_amdgcn_rcpf(1.0f + __expf(-x));
}
__device__ inline float ftanh(float x) {
  float e = __expf(2.0f * x);
  return 1.0f - 2.0f * __builtin_amdgcn_rcpf(e + 1.0f);
}

// ---------- transpose+convert: src [K][N] f32 -> dst [N][Kpad] bf16 (zero pad) ----------
__global__ __launch_bounds__(256) void transpose_bf16(const float* __restrict__ src,
                                                      unsigned short* __restrict__ dst,
                                                      int K, int N, int Kpad) {
  __shared__ float tile[32][33];
  int n0 = blockIdx.x * 32, k0 = blockIdx.y * 32;
  int tx = threadIdx.x & 31, ty = threadIdx.x >> 5;  // 32 x 8
#pragma unroll
  for (int i = 0; i < 32; i += 8) {
    int k = k0 + ty + i, n = n0 + tx;
    tile[ty + i][tx] = (k < K) ? src[(size_t)k * N + n] : 0.0f;
  }
  __syncthreads();
#pragma unroll
  for (int i = 0; i < 32; i += 8) {
    int n = n0 + ty + i, k = k0 + tx;
    dst[(size_t)n * Kpad + k] = f2bf(tile[tx][ty + i]);
  }
}

// ---------- bf16 MFMA GEMM for xg1: rows gathered from emb + predicate flag ----------
__global__ __launch_bounds__(256) void gemm_xg1(const float* __restrict__ emb,
                                                const int* __restrict__ wid,
                                                const int* __restrict__ pred,
                                                const unsigned short* __restrict__ Bt,
                                                unsigned short* __restrict__ C,
                                                int Kpad) {
  int n0 = blockIdx.x * 64, m0 = blockIdx.y * 64;
  int tid = threadIdx.x, lane = tid & 63, w = tid >> 6;
  int wr = w >> 1, wc = w & 1;
  __shared__ __align__(16) char As[64 * ASTR];
  __shared__ __align__(16) char Bs[64 * ASTR];
  __shared__ int wids[64];
  __shared__ float pf[64];
  if (tid < 64) {
    wids[tid] = wid[m0 + tid];
    pf[tid] = (float)pred[m0 + tid];
  }
  __syncthreads();
  floatx4 acc[2][2];
#pragma unroll
  for (int a = 0; a < 2; a++)
#pragma unroll
    for (int b = 0; b < 2; b++) acc[a][b] = (floatx4){0.f, 0.f, 0.f, 0.f};

  int row = tid >> 2, part = tid & 3;
  for (int k0 = 0; k0 < Kpad; k0 += 32) {
    int kb = k0 + part * 8;
    const float* erow = emb + (size_t)wids[row] * 300;
    float f[8];
    if (kb + 8 <= 300) {
      const float4* p4 = (const float4*)(erow + kb);
      float4 x0 = p4[0], x1 = p4[1];
      f[0] = x0.x; f[1] = x0.y; f[2] = x0.z; f[3] = x0.w;
      f[4] = x1.x; f[5] = x1.y; f[6] = x1.z; f[7] = x1.w;
    } else {
#pragma unroll
      for (int j = 0; j < 8; j++) {
        int k = kb + j;
        f[j] = (k < 300) ? erow[k] : ((k == 300) ? pf[row] : 0.0f);
      }
    }
    short8 av;
#pragma unroll
    for (int j = 0; j < 8; j++) av[j] = (short)f2bf(f[j]);
    *(short8*)(As + row * ASTR + part * 16) = av;
    short8 bv = *(const short8*)(Bt + (size_t)(n0 + row) * Kpad + k0 + part * 8);
    *(short8*)(Bs + row * ASTR + part * 16) = bv;
    __syncthreads();
    short8 afr[2], bfr[2];
#pragma unroll
    for (int mr = 0; mr < 2; mr++) {
      int arow = wr * 32 + mr * 16 + (lane & 15);
      afr[mr] = *(const short8*)(As + arow * ASTR + (lane >> 4) * 16);
    }
#pragma unroll
    for (int nc = 0; nc < 2; nc++) {
      int bcol = wc * 32 + nc * 16 + (lane & 15);
      bfr[nc] = *(const short8*)(Bs + bcol * ASTR + (lane >> 4) * 16);
    }
#pragma unroll
    for (int mr = 0; mr < 2; mr++)
#pragma unroll
      for (int nc = 0; nc < 2; nc++)
        acc[mr][nc] = __builtin_amdgcn_mfma_f32_16x16x32_bf16(afr[mr], bfr[nc], acc[mr][nc], 0, 0, 0);
    __syncthreads();
  }
#pragma unroll
  for (int mr = 0; mr < 2; mr++)
#pragma unroll
    for (int nc = 0; nc < 2; nc++)
#pragma unroll
      for (int r = 0; r < 4; r++) {
        int rr = m0 + wr * 32 + mr * 16 + ((lane >> 4) << 2) + r;
        int cc = n0 + wc * 32 + nc * 16 + (lane & 15);
        C[(size_t)rr * G4 + cc] = f2bf(acc[mr][nc][r]);
      }
}

// ---------- combined tagged staging: h1(t-1) -> AhA, h2(t-2) -> AhB, ONE wait ----------
// Granule i (0..15): layer L=i>>3, ii=i&7; 4 tagged u32 at elems 8*c16+128*(ii>>1)+4*(ii&1).
// Valid when all 4 high-16 tags == want; untag and place into swizzled LDS row.
__device__ __forceinline__ void stage2(const unsigned int* baseA, const unsigned int* baseB,
                                       unsigned want, char* AhRowA, char* AhRowB,
                                       int sw, int c16) {
  unsigned done = 0;
  while (done != 0xFFFFu) {
    intx4 v[16];
#pragma unroll
    for (int i = 0; i < 16; i++) {
      if (!(done & (1u << i))) {
        const unsigned int* p =
            (i < 8 ? baseA : baseB) + 8 * c16 + 128 * ((i & 7) >> 1) + 4 * (i & 1);
        asm volatile("global_load_dwordx4 %0, %1, off sc0 sc1" : "=v"(v[i]) : "v"(p) : "memory");
      }
    }
    asm volatile("s_waitcnt vmcnt(0)" ::: "memory");
#pragma unroll
    for (int i = 0; i < 16; i++) {
      if (!(done & (1u << i))) {
        intx4 a = v[i];
        unsigned u0 = (unsigned)a.x, u1 = (unsigned)a.y, u2 = (unsigned)a.z, u3 = (unsigned)a.w;
        bool ok = ((u0 >> 16) == want) & ((u1 >> 16) == want) & ((u2 >> 16) == want) &
                  ((u3 >> 16) == want);
        if (ok) {
          unsigned lo = (u0 & 0xffffu) | (u1 << 16);
          unsigned hi = (u2 & 0xffffu) | (u3 << 16);
          int s = c16 + 16 * ((i & 7) >> 1);
          uint2 pp; pp.x = lo; pp.y = hi;
          *(uint2*)((i < 8 ? AhRowA : AhRowB) + ((s * 16) ^ sw) + (i & 1) * 8) = pp;
          done |= (1u << i);
        }
      }
    }
    if (done != 0xFFFFu) __builtin_amdgcn_s_sleep(1);
  }
}

// ---------- merged persistent dual-layer masked LSTM ----------
// grid = 256 = #CUs (1 block/CU, 4 waves, no CU sharing). Block (bgrp=blk&7, jblk=blk>>3)
// computes, at iteration t: layer1 step t AND layer2 step t-1 for rows b0..b0+15, j-slice j0..+15.
// Both need exactly {h1(t-1), h2(t-2)} = what peers stored at end of iteration t-1 -> ONE
// tagged stage per step from a depth-2 ring ex[slot][layer][128][512] (memset per launch;
// within-launch overwrite-before-consume impossible by lockstep induction).
// W2 folded into registers: g2 = h1(t-1)@W2 + h2(t-2)@U2 + b2 (gemm2 dispatch eliminated).
// 48 weight fragments = 192 VGPR/lane; __launch_bounds__(256,1) -> 512-VGPR budget, no spill.
__global__ __launch_bounds__(256, 1) void lstm_merged(
    const unsigned short* __restrict__ xg1,
    const unsigned short* __restrict__ Ut1, const float* __restrict__ b1,
    const unsigned short* __restrict__ Wt2, const unsigned short* __restrict__ Ut2,
    const float* __restrict__ b2, const int* __restrict__ wid,
    unsigned int* ex, unsigned short* h2seq) {
  const int blk = blockIdx.x;
  const int bgrp = blk & 7, jblk = blk >> 3;
  const int b0 = bgrp * 16, j0 = jblk * 16;
  const int tid = threadIdx.x, lane = tid & 63, w = tid >> 6;

  __shared__ __align__(16) char AhA[16 * 1024];  // h1(t-1) bf16 [16][512], swizzled
  __shared__ __align__(16) char AhB[16 * 1024];  // h2(t-2)
  __shared__ float g1s[4][16][16];
  __shared__ float g2s[4][16][16];
  __shared__ float cst1[16][16];
  __shared__ float cst2[16][16];
  __shared__ __align__(16) unsigned short xgt[4][16][16];

  const int row = tid >> 4, c16 = tid & 15;
  const int sw = (row & 7) << 4;
  char* AhRowA = AhA + row * 1024;
  char* AhRowB = AhB + row * 1024;
  const int ucol = w * 512 + j0 + (lane & 15);
  const int* widp = wid + (size_t)(b0 + row) * T_SEQ;

  // weights: wave w owns gate w, cols j0..j0+15 of U1, W2, U2 (16 frags each)
  short8 uf1[16], wf2[16], uf2[16];
  {
    const unsigned short* p1 = Ut1 + (size_t)ucol * 512 + ((lane >> 4) * 8);
    const unsigned short* p2 = Wt2 + (size_t)ucol * 512 + ((lane >> 4) * 8);
    const unsigned short* p3 = Ut2 + (size_t)ucol * 512 + ((lane >> 4) * 8);
#pragma unroll
    for (int kk = 0; kk < 16; kk++) {
      uf1[kk] = *(const short8*)(p1 + kk * 32);
      wf2[kk] = *(const short8*)(p2 + kk * 32);
      uf2[kk] = *(const short8*)(p3 + kk * 32);
    }
  }
  float b1v = b1[ucol], b2v = b2[ucol];
  cst1[row][c16] = 0.0f;
  cst2[row][c16] = 0.0f;
  {
    short8 z = {0, 0, 0, 0, 0, 0, 0, 0};
    for (int i = tid; i < 1024; i += 256) {
      *(short8*)(AhA + i * 16) = z;
      *(short8*)(AhB + i * 16) = z;
    }
  }
  __syncthreads();

  // xg prefetch (uint2 = 4 bf16 per thread per step)
  int xg_g = tid >> 6, xg_rw = (tid >> 2) & 15, xg_part = tid & 3;
  uint2 xpf = *(const uint2*)(xg1 + ((size_t)(b0 + xg_rw) * T_SEQ + 0) * G4 + xg_g * 512 + j0 +
                              xg_part * 4);
  int mcur = widp[0];  // mask m(t) for layer1
  int mprev = 0;       // mask m(t-1) for layer2

  const size_t SLOT = (size_t)2 * 128 * 512;  // u32 per ring slot

  for (int t = 0; t <= T_SEQ; t++) {
    if (t > 0) {
      const unsigned int* baseA = ex + ((t - 1) & 1) * SLOT + (size_t)(b0 + row) * 512;
      const unsigned int* baseB = baseA + (size_t)128 * 512;
      stage2(baseA, baseB, (unsigned)t, AhRowA, AhRowB, sw, c16);
    }
    if (t < T_SEQ) {
      *(uint2*)(&xgt[xg_g][xg_rw][xg_part * 4]) = xpf;
      if (t + 1 < T_SEQ)
        xpf = *(const uint2*)(xg1 + ((size_t)(b0 + xg_rw) * T_SEQ + (t + 1)) * G4 + xg_g * 512 +
                              j0 + xg_part * 4);
    }
    __syncthreads();

    // MFMA phase: AhA feeds BOTH U1 (layer1) and W2 (layer2); AhB feeds U2.
    floatx4 acc1 = (floatx4){0.f, 0.f, 0.f, 0.f};
    floatx4 acc2 = (floatx4){0.f, 0.f, 0.f, 0.f};
    {
      int frow = lane & 15, kbase = (lane >> 4) * 16, fsw = (frow & 7) << 4;
#pragma unroll
      for (int kk = 0; kk < 16; kk++) {
        short8 a = *(const short8*)(AhA + frow * 1024 + ((kk * 64 + kbase) ^ fsw));
        acc1 = __builtin_amdgcn_mfma_f32_16x16x32_bf16(a, uf1[kk], acc1, 0, 0, 0);
        acc2 = __builtin_amdgcn_mfma_f32_16x16x32_bf16(a, wf2[kk], acc2, 0, 0, 0);
      }
#pragma unroll
      for (int kk = 0; kk < 16; kk++) {
        short8 bb = *(const short8*)(AhB + frow * 1024 + ((kk * 64 + kbase) ^ fsw));
        acc2 = __builtin_amdgcn_mfma_f32_16x16x32_bf16(bb, uf2[kk], acc2, 0, 0, 0);
      }
    }
#pragma unroll
    for (int r = 0; r < 4; r++) {
      int grow = ((lane >> 4) << 2) + r, gcol = lane & 15;
      if (t < T_SEQ) g1s[w][grow][gcol] = acc1[r] + b1v + bf2f(xgt[w][grow][gcol]);
      if (t > 0) g2s[w][grow][gcol] = acc2[r] + b2v;
    }
    __syncthreads();

    unsigned short h1b = 0, h2b = 0;
    if (t < T_SEQ) {  // layer1 step t
      float gi = g1s[0][row][c16], gf = g1s[1][row][c16];
      float gc = g1s[2][row][c16], go = g1s[3][row][c16];
      float iv = fsigmoid(gi), fv = fsigmoid(gf), cd = ftanh(gc), ov = fsigmoid(go);
      float cold = cst1[row][c16];
      float cn = fv * cold + iv * cd;
      float hn = ov * ftanh(cn);
      if (mcur == 0) {
        cn = cold;
        hn = bf2f(*(const unsigned short*)(AhRowA + (((j0 + c16) * 2) ^ sw)));
      }
      cst1[row][c16] = cn;
      h1b = f2bf(hn);
    }
    if (t > 0) {  // layer2 step t-1
      float gi = g2s[0][row][c16], gf = g2s[1][row][c16];
      float gc = g2s[2][row][c16], go = g2s[3][row][c16];
      float iv = fsigmoid(gi), fv = fsigmoid(gf), cd = ftanh(gc), ov = fsigmoid(go);
      float cold = cst2[row][c16];
      float cn = fv * cold + iv * cd;
      float hn = ov * ftanh(cn);
      if (mprev == 0) {
        cn = cold;
        hn = bf2f(*(const unsigned short*)(AhRowB + (((j0 + c16) * 2) ^ sw)));
      }
      cst2[row][c16] = cn;
      h2b = f2bf(hn);
      h2seq[((size_t)(b0 + row) * T_SEQ + (t - 1)) * HID + j0 + c16] = h2b;
    }

    if (t < T_SEQ) {  // publish h1(t) and h2(t-1) with tag t+1 into slot t&1
      unsigned tag = ((unsigned)(t + 1)) << 16;
      unsigned v1 = tag | h1b, v2 = tag | h2b;
      unsigned int* d1 = ex + (t & 1) * SLOT + (size_t)(b0 + row) * 512 + j0 + c16;
      unsigned int* d2 = d1 + (size_t)128 * 512;
      asm volatile("global_store_dword %0, %1, off sc0 sc1" ::"v"(d1), "v"(v1) : "memory");
      asm volatile("global_store_dword %0, %1, off sc0 sc1" ::"v"(d2), "v"(v2) : "memory");
    }
    mprev = mcur;
    mcur = (t + 1 < T_SEQ) ? widp[t + 1] : 0;
    __syncthreads();  // protect AhA/AhB reads from next iteration's stage writes
  }
}

// ---------- dense (512->96) + softmax, MFMA ----------
__global__ __launch_bounds__(256) void dense_softmax(const unsigned short* __restrict__ h2,
                                                     const unsigned short* __restrict__ Wdt,
                                                     const float* __restrict__ bd,
                                                     float* __restrict__ out) {
  int m0 = blockIdx.x * 64;
  int tid = threadIdx.x, lane = tid & 63, w = tid >> 6;
  __shared__ __align__(16) char As[64 * ASTR];
  __shared__ __align__(16) char Bs[96 * ASTR];
  floatx4 acc[6];
#pragma unroll
  for (int i = 0; i < 6; i++) acc[i] = (floatx4){0.f, 0.f, 0.f, 0.f};
  for (int k0 = 0; k0 < 512; k0 += 32) {
    {
      int row = tid >> 2, part = tid & 3;
      short8 v = *(const short8*)(h2 + (size_t)(m0 + row) * 512 + k0 + part * 8);
      *(short8*)(As + row * ASTR + part * 16) = v;
    }
    for (int u = tid; u < 96 * 4; u += 256) {
      int col = u >> 2, part = u & 3;
      short8 v = *(const short8*)(Wdt + (size_t)col * 512 + k0 + part * 8);
      *(short8*)(Bs + col * ASTR + part * 16) = v;
    }
    __syncthreads();
    int arow = w * 16 + (lane & 15);
    short8 a = *(const short8*)(As + arow * ASTR + (lane >> 4) * 16);
#pragma unroll
    for (int nc = 0; nc < 6; nc++) {
      int bcol = nc * 16 + (lane & 15);
      short8 b = *(const short8*)(Bs + bcol * ASTR + (lane >> 4) * 16);
      acc[nc] = __builtin_amdgcn_mfma_f32_16x16x32_bf16(a, b, acc[nc], 0, 0, 0);
    }
    __syncthreads();
  }
  float bv[6];
#pragma unroll
  for (int nc = 0; nc < 6; nc++) bv[nc] = bd[nc * 16 + (lane & 15)];
#pragma unroll
  for (int r = 0; r < 4; r++) {
    float v[6];
    float mx = -1e30f;
#pragma unroll
    for (int nc = 0; nc < 6; nc++) {
      v[nc] = acc[nc][r] + bv[nc];
      mx = fmaxf(mx, v[nc]);
    }
#pragma unroll
    for (int d = 1; d < 16; d <<= 1) mx = fmaxf(mx, __shfl_xor(mx, d));
    float s = 0.f;
#pragma unroll
    for (int nc = 0; nc < 6; nc++) {
      v[nc] = __expf(v[nc] - mx);
      s += v[nc];
    }
#pragma unroll
    for (int d = 1; d < 16; d <<= 1) s += __shfl_xor(s, d);
    float inv = 1.0f / s;
    int rr = m0 + w * 16 + ((lane >> 4) << 2) + r;
#pragma unroll
    for (int nc = 0; nc < 6; nc++) out[(size_t)rr * 96 + nc * 16 + (lane & 15)] = v[nc] * inv;
  }
}

extern "C" void kernel_launch(void* const* d_in, const int* in_sizes, int n_in,
                              void* d_out, int out_size, void* d_ws, size_t ws_size,
                              hipStream_t stream) {
  (void)in_sizes; (void)n_in; (void)out_size; (void)ws_size;
  const int* word_ids = (const int*)d_in[0];
  const int* pred = (const int*)d_in[1];
  const float* emb = (const float*)d_in[2];
  const float* W1 = (const float*)d_in[3];
  const float* U1 = (const float*)d_in[4];
  const float* b1 = (const float*)d_in[5];
  const float* W2 = (const float*)d_in[6];
  const float* U2 = (const float*)d_in[7];
  const float* b2 = (const float*)d_in[8];
  const float* Wd = (const float*)d_in[9];
  const float* bd = (const float*)d_in[10];
  float* out = (float*)d_out;

  const size_t EXBYTES = (size_t)2 * 2 * 128 * 512 * 4;  // 1 MB depth-2 ring

  char* p = (char*)d_ws;
  unsigned short* xg = (unsigned short*)p;   p += (size_t)32768 * 2048 * 2;  // 128MB
  unsigned short* h2s = (unsigned short*)p;  p += (size_t)32768 * 512 * 2;   // 32MB
  unsigned int* ex = (unsigned int*)p;       p += EXBYTES;
  unsigned short* Ut1 = (unsigned short*)p;  p += (size_t)2048 * 512 * 2;
  unsigned short* Ut2 = (unsigned short*)p;  p += (size_t)2048 * 512 * 2;
  unsigned short* Wt1 = (unsigned short*)p;  p += (size_t)2048 * 320 * 2;
  unsigned short* Wt2 = (unsigned short*)p;  p += (size_t)2048 * 512 * 2;
  unsigned short* Wdt = (unsigned short*)p;  p += (size_t)96 * 512 * 2;

  // clear exchange ring every launch: kills cross-replay stale-tag race
  hipMemsetAsync(ex, 0, EXBYTES, stream);

  hipLaunchKernelGGL(transpose_bf16, dim3(64, 16), dim3(256), 0, stream, U1, Ut1, 512, 2048, 512);
  hipLaunchKernelGGL(transpose_bf16, dim3(64, 16), dim3(256), 0, stream, U2, Ut2, 512, 2048, 512);
  hipLaunchKernelGGL(transpose_bf16, dim3(64, 10), dim3(256), 0, stream, W1, Wt1, 301, 2048, 320);
  hipLaunchKernelGGL(transpose_bf16, dim3(64, 16), dim3(256), 0, stream, W2, Wt2, 512, 2048, 512);
  hipLaunchKernelGGL(transpose_bf16, dim3(3, 16), dim3(256), 0, stream, Wd, Wdt, 512, 96, 512);

  hipLaunchKernelGGL(gemm_xg1, dim3(32, 512), dim3(256), 0, stream,
                     emb, word_ids, pred, Wt1, xg, 320);
  hipLaunchKernelGGL(lstm_merged, dim3(256), dim3(256), 0, stream,
                     xg, Ut1, b1, Wt2, Ut2, b2, word_ids, ex, h2s);
  hipLaunchKernelGGL(dense_softmax, dim3(512), dim3(256), 0, stream, h2s, Wdt, bd, out);
}